// Round 2
// 29990.164 us; speedup vs baseline: 1.2087x; 1.2087x over previous
//
#include <hip/hip_runtime.h>
#include <math.h>

#define BB 128
#define TT 256
#define HH 512
#define VV 32
#define MLEN 128
#define SLOT 65536          // HH*BB floats

// Static LDS layout (floats), 130048 bytes total (gfx950: 160 KiB/WG addressable):
//  WT @0      : 24576  persistent weight tiles (enc: 36 rows x 512, dec: 24 rows x 1024)
//  QT @24576  : 2048   persistent qW tile (4 rows x 512)
//  PR @26624  : 1792   partial-sum rows (28 x 64)
//  SC @28416  : 4096   phase scratch (A2 softmax/attn staging, D logits staging)
#define WT_OFF 0
#define QT_OFF 24576
#define PR_OFF 26624
#define SC_OFF 28416
#define SM_FLOATS 32512

typedef long long ll;

struct P {
    const float *x, *emb;
    const float *eWih0, *eWhh0, *ebih0, *ebhh0;
    const float *eWih1, *eWhh1, *ebih1, *ebhh1;
    const float *dWih0, *dWhh0, *dbih0, *dbhh0;
    const float *dWih1, *dWhh1, *dbih1, *dbhh1;
    const float *qW, *qb, *outW, *outb;
    float *ws;
    float *vecO, *hidO, *attnO;
};

__device__ __forceinline__ float sigf(float v) { return 1.0f / (1.0f + __expf(-v)); }

// device-coherent (LLC) relaxed ops
__device__ __forceinline__ float ldA(const float* p) {
    return __hip_atomic_load(p, __ATOMIC_RELAXED, __HIP_MEMORY_SCOPE_AGENT);
}
__device__ __forceinline__ void stA(float* p, float v) {
    __hip_atomic_store(p, v, __ATOMIC_RELAXED, __HIP_MEMORY_SCOPE_AGENT);
}
__device__ __forceinline__ int ldAi(const int* p) {
    return __hip_atomic_load(p, __ATOMIC_RELAXED, __HIP_MEMORY_SCOPE_AGENT);
}
__device__ __forceinline__ void stAi(int* p, int v) {
    __hip_atomic_store(p, v, __ATOMIC_RELAXED, __HIP_MEMORY_SCOPE_AGENT);
}

// relaxed-only two-level grid barrier (unchanged from verified baseline)
__device__ __forceinline__ void gbar(int* W, int target) {
    __syncthreads();
    if (threadIdx.x == 0) {
        int par = target & 1;
        int g = blockIdx.x & 15;
        int* gc = W + 32 + (par * 16 + g) * 32;
        if (__hip_atomic_fetch_add(gc, 1, __ATOMIC_RELAXED, __HIP_MEMORY_SCOPE_AGENT) == 15) {
            __hip_atomic_store(gc, 0, __ATOMIC_RELAXED, __HIP_MEMORY_SCOPE_AGENT);
            int* rc = W + 1056 + par * 32;
            if (__hip_atomic_fetch_add(rc, 1, __ATOMIC_RELAXED, __HIP_MEMORY_SCOPE_AGENT) == 15) {
                __hip_atomic_store(rc, 0, __ATOMIC_RELAXED, __HIP_MEMORY_SCOPE_AGENT);
                __hip_atomic_store(W, target, __ATOMIC_RELAXED, __HIP_MEMORY_SCOPE_AGENT);
            }
        }
        while (__hip_atomic_load(W, __ATOMIC_RELAXED, __HIP_MEMORY_SCOPE_AGENT) < target)
            __builtin_amdgcn_s_sleep(2);
    }
    __syncthreads();
}

__global__ __launch_bounds__(512, 1) void kmain(P p) {
    __shared__ __align__(16) float smu[SM_FLOATS];
    const int tid = threadIdx.x;
    const int lane = tid & 63;
    const int wv = tid >> 6;
    const int blk = blockIdx.x;

    int* W = (int*)p.ws;
    int* tok = W + 4096;
    float* f = (float*)p.ws + 8192;
    float* eh0 = f;                       // 2 slots
    float* eh1 = f + 2 * SLOT;            // 2 slots
    float* inp = f + 4 * SLOT;            // ctx [512 d][128 b]
    float* qbm = f + 5 * SLOT;            // [512 j][128 b]
    float* scoresB = f + 6 * SLOT;        // [256 t][128 b]
    float* T = f + 6 * SLOT + SLOT / 2;   // [3][512][32] emb-projection table
    float* xT = T + 3 * HH * VV;          // [256 t][2][128 b]
    float* encO = f + (SLOT / 4) * 33;    // [256 t][512 j][128 b]

    const float4* t4 = (const float4*)smu;
    const float4* t4q = (const float4*)(smu + QT_OFF);

    const int jg = blk >> 1;              // 0..127, owns j = 4*jg..4*jg+3
    const int bh = blk & 1;
    const int b2 = bh * 64 + lane;
    int bar = 0;

    // ================= INIT =================
    {
        // zero 4 h slots
        stA(eh0 + blk * 1024 + tid, 0.0f);
        stA(eh0 + blk * 1024 + 512 + tid, 0.0f);
        // xT transpose
        if (tid < 256) {
            int idx = blk * 256 + tid;
            int t = idx >> 8, c = (idx >> 7) & 1, b = idx & 127;
            stA(xT + idx, p.x[((ll)b * TT + t) * 2 + c]);
        }
        // T table: T[(g*512+j)*32+v] = dot(dWih0[g*512+j][0:512], emb[v])
        if (tid < 192) {
            int unit = blk * 192 + tid;
            int v = unit & 31, gj = unit >> 5;
            const float* wrow = p.dWih0 + (ll)gj * 1024;
            const float* erow = p.emb + (ll)v * HH;
            float acc = 0.0f;
#pragma unroll 8
            for (int d = 0; d < HH; ++d) acc = fmaf(wrow[d], erow[d], acc);
            stA(T + unit, acc);
        }
        // persistent qW tile
#pragma unroll
        for (int jl = 0; jl < 4; ++jl)
            smu[QT_OFF + jl * 512 + tid] = p.qW[((ll)(jg * 4 + jl)) * HH + tid];
        // persistent encoder weights: rows 0..23 = (Whh0 g0..2 | Wih1 g0..2), 24..35 = Whh1
#pragma unroll
        for (int r = 0; r < 24; ++r) {
            int g = r >> 2, jl = r & 3, j = jg * 4 + jl;
            const float* src = (g < 3) ? (p.eWhh0 + (ll)(g * HH + j) * HH)
                                       : (p.eWih1 + (ll)((g - 3) * HH + j) * HH);
            smu[WT_OFF + r * 512 + tid] = src[tid];
        }
#pragma unroll
        for (int r = 0; r < 12; ++r) {
            int g = r >> 2, jl = r & 3, j = jg * 4 + jl;
            smu[WT_OFF + (24 + r) * 512 + tid] = p.eWhh1[(ll)(g * HH + j) * HH + tid];
        }
        gbar(W, ++bar);
    }

    // ================= ENCODER: 257 pipelined steps, single merged pass =================
    for (int t = 0; t <= TT; ++t) {
        const float* h0s = eh0 + (((t + 1) & 1) ? SLOT : 0);
        float*       h0d = eh0 + ((t & 1) ? SLOT : 0);
        const float* h1s = eh1 + (((t + 1) & 1) ? SLOT : 0);
        float*       h1d = eh1 + ((t & 1) ? SLOT : 0);

        smu[PR_OFF + tid] = 0.0f;
        smu[PR_OFF + 512 + tid] = 0.0f;
        smu[PR_OFF + 1024 + tid] = 0.0f;
        if (tid < 256) smu[PR_OFF + 1536 + tid] = 0.0f;
        __syncthreads();

        // merged stream with 2-deep register prefetch:
        //   h0s feeds rows 0..23 (l0 h-gates + l1 i-gates), h1s feeds rows 24..35
        {
            const int ds0 = wv * 64;
            float acc[36];
#pragma unroll
            for (int r = 0; r < 36; ++r) acc[r] = 0.0f;
            float av[2][8], bv[2][8];
#pragma unroll
            for (int u = 0; u < 8; ++u) av[0][u] = ldA(h0s + (ll)(ds0 + u) * BB + b2);
#pragma unroll
            for (int u = 0; u < 8; ++u) bv[0][u] = ldA(h1s + (ll)(ds0 + u) * BB + b2);
#pragma unroll
            for (int c = 0; c < 8; ++c) {
                const int cb = c & 1, pb = cb ^ 1;
                if (c < 7) {
                    const int dn = ds0 + (c + 1) * 8;
#pragma unroll
                    for (int u = 0; u < 8; ++u) av[pb][u] = ldA(h0s + (ll)(dn + u) * BB + b2);
#pragma unroll
                    for (int u = 0; u < 8; ++u) bv[pb][u] = ldA(h1s + (ll)(dn + u) * BB + b2);
                }
                const int db = ds0 + c * 8;
#pragma unroll
                for (int h2 = 0; h2 < 2; ++h2) {
                    const int q4 = (db + h2 * 4) >> 2;
#pragma unroll
                    for (int r = 0; r < 24; ++r) {
                        float4 w = t4[r * 128 + q4];
                        acc[r] = fmaf(w.x, av[cb][h2 * 4 + 0], acc[r]);
                        acc[r] = fmaf(w.y, av[cb][h2 * 4 + 1], acc[r]);
                        acc[r] = fmaf(w.z, av[cb][h2 * 4 + 2], acc[r]);
                        acc[r] = fmaf(w.w, av[cb][h2 * 4 + 3], acc[r]);
                    }
#pragma unroll
                    for (int r = 0; r < 12; ++r) {
                        float4 w = t4[(24 + r) * 128 + q4];
                        acc[24 + r] = fmaf(w.x, bv[cb][h2 * 4 + 0], acc[24 + r]);
                        acc[24 + r] = fmaf(w.y, bv[cb][h2 * 4 + 1], acc[24 + r]);
                        acc[24 + r] = fmaf(w.z, bv[cb][h2 * 4 + 2], acc[24 + r]);
                        acc[24 + r] = fmaf(w.w, bv[cb][h2 * 4 + 3], acc[24 + r]);
                    }
                }
            }
#pragma unroll
            for (int r = 0; r < 24; ++r)
                unsafeAtomicAdd(&smu[PR_OFF + r * 64 + lane], acc[r]);
#pragma unroll
            for (int r = 0; r < 12; ++r) {
                int g = r >> 2;
                int prow = (g < 2) ? (12 + g * 4) : 24;
                unsafeAtomicAdd(&smu[PR_OFF + (prow + (r & 3)) * 64 + lane], acc[24 + r]);
            }
        }
        __syncthreads();

        // finalize: waves 0..3 do layer0, waves 4..7 do layer1 (independent)
        if (wv < 4) {
            if (t < TT) {
                int jl = wv, j = jg * 4 + jl;
                float* pr = smu + PR_OFF;
                float hr = pr[(0 + jl) * 64 + lane] + p.ebhh0[j];
                float hz = pr[(4 + jl) * 64 + lane] + p.ebhh0[HH + j];
                float hn = pr[(8 + jl) * 64 + lane] + p.ebhh0[2 * HH + j];
                float x0 = xT[t * 256 + b2], x1 = xT[t * 256 + 128 + b2];
                float ir = fmaf(p.eWih0[j * 2], x0, fmaf(p.eWih0[j * 2 + 1], x1, p.ebih0[j]));
                float iz = fmaf(p.eWih0[(HH + j) * 2], x0, fmaf(p.eWih0[(HH + j) * 2 + 1], x1, p.ebih0[HH + j]));
                float in_ = fmaf(p.eWih0[(2 * HH + j) * 2], x0, fmaf(p.eWih0[(2 * HH + j) * 2 + 1], x1, p.ebih0[2 * HH + j]));
                float r = sigf(ir + hr), z = sigf(iz + hz);
                float n = tanhf(in_ + r * hn);
                float hp = ldA(h0s + (ll)j * BB + b2);
                stA(h0d + (ll)j * BB + b2, (1.0f - z) * n + z * hp);
            }
        } else if (t >= 1) {
            int jl = wv - 4, j = jg * 4 + jl;
            float* pr = smu + PR_OFF;
            float rs = pr[(12 + jl) * 64 + lane] + p.ebih1[j] + p.ebhh1[j];
            float zs = pr[(16 + jl) * 64 + lane] + p.ebih1[HH + j] + p.ebhh1[HH + j];
            float in1 = pr[(20 + jl) * 64 + lane] + p.ebih1[2 * HH + j];
            float hn1 = pr[(24 + jl) * 64 + lane] + p.ebhh1[2 * HH + j];
            float r = sigf(rs), z = sigf(zs);
            float n = tanhf(in1 + r * hn1);
            float hp = ldA(h1s + (ll)j * BB + b2);
            float hv = (1.0f - z) * n + z * hp;
            stA(h1d + (ll)j * BB + b2, hv);
            stA(encO + ((ll)(t - 1) * HH + j) * BB + b2, hv);
        }
        gbar(W, ++bar);
    }

    // ================= DEC-INIT: stage decoder weights + query from enc h1, tok=0 =================
    {
        const float* h1c = eh1;  // slot 0
        if (tid < 256) smu[PR_OFF + tid] = 0.0f;
        // persistent decoder weights: rows 0..11 = L0 (Wih0-ctx | Whh0), 12..23 = L1 (Wih1 | Whh1)
#pragma unroll
        for (int r = 0; r < 12; ++r) {
            int g = r >> 2, jl = r & 3, j = jg * 4 + jl;
            smu[WT_OFF + r * 1024 + tid]              = p.dWih0[(ll)(g * HH + j) * 1024 + 512 + tid];
            smu[WT_OFF + r * 1024 + 512 + tid]        = p.dWhh0[(ll)(g * HH + j) * HH + tid];
            smu[WT_OFF + (12 + r) * 1024 + tid]       = p.dWih1[(ll)(g * HH + j) * HH + tid];
            smu[WT_OFF + (12 + r) * 1024 + 512 + tid] = p.dWhh1[(ll)(g * HH + j) * HH + tid];
        }
        __syncthreads();
        {
            const int ds0 = wv * 64;
            float acc[4] = {0, 0, 0, 0};
            float av[8];
            for (int c = 0; c < 8; ++c) {
                int db = ds0 + c * 8;
#pragma unroll
                for (int u = 0; u < 8; ++u) av[u] = ldA(h1c + (ll)(db + u) * BB + b2);
#pragma unroll
                for (int h2 = 0; h2 < 2; ++h2) {
                    int q4 = (db + h2 * 4) >> 2;
#pragma unroll
                    for (int jl = 0; jl < 4; ++jl) {
                        float4 w = t4q[jl * 128 + q4];
                        acc[jl] = fmaf(w.x, av[h2 * 4 + 0], acc[jl]);
                        acc[jl] = fmaf(w.y, av[h2 * 4 + 1], acc[jl]);
                        acc[jl] = fmaf(w.z, av[h2 * 4 + 2], acc[jl]);
                        acc[jl] = fmaf(w.w, av[h2 * 4 + 3], acc[jl]);
                    }
                }
            }
#pragma unroll
            for (int jl = 0; jl < 4; ++jl)
                unsafeAtomicAdd(&smu[PR_OFF + jl * 64 + lane], acc[jl]);
        }
        __syncthreads();
        if (wv < 4) {
            int j = jg * 4 + wv;
            stA(qbm + (ll)j * BB + b2, smu[PR_OFF + wv * 64 + lane] + p.qb[j]);
        }
        if (blk == 128 && tid < BB) stAi(tok + tid, 0);
        gbar(W, ++bar);
    }

    // ================= DECODER: 128 steps x 5 phases =================
    for (int s = 0; s < MLEN; ++s) {
        const float* h0s = eh0 + (((s + 1) & 1) ? SLOT : 0);
        float*       g0d = eh0 + ((s & 1) ? SLOT : 0);
        const float* h1s = eh1 + ((s & 1) ? SLOT : 0);
        float*       h1d = eh1 + (((s + 1) & 1) ? SLOT : 0);

        // --- A1: scores, all 256 blocks, 2 t each (encO reads: plain/cached) ---
        {
            const int t0 = (blk >> 1) * 2;
            if (tid < 128) smu[PR_OFF + tid] = 0.0f;
            __syncthreads();
            const int js = wv * 64;
            float a0 = 0.0f, a1 = 0.0f;
            float qv[2][8], e0[2][8], e1[2][8];
#pragma unroll
            for (int u = 0; u < 8; ++u) {
                qv[0][u] = ldA(qbm + (ll)(js + u) * BB + b2);
                e0[0][u] = encO[((ll)t0 * HH + js + u) * BB + b2];
                e1[0][u] = encO[((ll)(t0 + 1) * HH + js + u) * BB + b2];
            }
#pragma unroll
            for (int c = 0; c < 8; ++c) {
                const int cb = c & 1, pb = cb ^ 1;
                if (c < 7) {
                    const int jn = js + (c + 1) * 8;
#pragma unroll
                    for (int u = 0; u < 8; ++u) {
                        qv[pb][u] = ldA(qbm + (ll)(jn + u) * BB + b2);
                        e0[pb][u] = encO[((ll)t0 * HH + jn + u) * BB + b2];
                        e1[pb][u] = encO[((ll)(t0 + 1) * HH + jn + u) * BB + b2];
                    }
                }
#pragma unroll
                for (int u = 0; u < 8; ++u) {
                    a0 = fmaf(qv[cb][u], e0[cb][u], a0);
                    a1 = fmaf(qv[cb][u], e1[cb][u], a1);
                }
            }
            unsafeAtomicAdd(&smu[PR_OFF + lane], a0);
            unsafeAtomicAdd(&smu[PR_OFF + 64 + lane], a1);
            __syncthreads();
            if (wv < 2)
                stA(scoresB + (ll)(t0 + wv) * BB + b2, smu[PR_OFF + wv * 64 + lane]);
        }
        gbar(W, ++bar);

        // --- A2: softmax + context (all 256 blocks); blocks<16 write attnO ---
        {
            const int d0 = jg * 4;
            float sv[32];
#pragma unroll
            for (int k = 0; k < 32; ++k) sv[k] = ldA(scoresB + (ll)(wv * 32 + k) * BB + b2);
            if (tid < 256) smu[PR_OFF + tid] = 0.0f;
            float mp = sv[0];
#pragma unroll
            for (int k = 1; k < 32; ++k) mp = fmaxf(mp, sv[k]);
            smu[SC_OFF + wv * 64 + lane] = mp;
            __syncthreads();
            float m = smu[SC_OFF + lane];
#pragma unroll
            for (int u = 1; u < 8; ++u) m = fmaxf(m, smu[SC_OFF + u * 64 + lane]);
            float e[32], lp = 0.0f;
#pragma unroll
            for (int k = 0; k < 32; ++k) { e[k] = __expf(sv[k] - m); lp += e[k]; }
            smu[SC_OFF + 512 + wv * 64 + lane] = lp;
            __syncthreads();
            float l = smu[SC_OFF + 512 + lane];
#pragma unroll
            for (int u = 1; u < 8; ++u) l += smu[SC_OFF + 512 + u * 64 + lane];
            float rl = 1.0f / l;
            if (blk < 16 && wv == jg) {
#pragma unroll
                for (int k = 0; k < 32; ++k) smu[SC_OFF + 1024 + k * 65 + lane] = e[k] * rl;
            }
            // context: chunked 2-deep prefetch, encO reads plain/cached
            float c4[4] = {0, 0, 0, 0};
            float ev[2][32];
#pragma unroll
            for (int u = 0; u < 8; ++u) {
                const float* Ep = encO + ((ll)(wv * 32 + u) * HH + d0) * BB + b2;
#pragma unroll
                for (int q = 0; q < 4; ++q) ev[0][u * 4 + q] = Ep[q * BB];
            }
#pragma unroll
            for (int kb = 0; kb < 4; ++kb) {
                const int cb = kb & 1, pb = cb ^ 1;
                if (kb < 3) {
#pragma unroll
                    for (int u = 0; u < 8; ++u) {
                        const float* Ep = encO + ((ll)(wv * 32 + (kb + 1) * 8 + u) * HH + d0) * BB + b2;
#pragma unroll
                        for (int q = 0; q < 4; ++q) ev[pb][u * 4 + q] = Ep[q * BB];
                    }
                }
#pragma unroll
                for (int u = 0; u < 8; ++u) {
                    const int k = kb * 8 + u;
                    c4[0] = fmaf(e[k], ev[cb][u * 4 + 0], c4[0]);
                    c4[1] = fmaf(e[k], ev[cb][u * 4 + 1], c4[1]);
                    c4[2] = fmaf(e[k], ev[cb][u * 4 + 2], c4[2]);
                    c4[3] = fmaf(e[k], ev[cb][u * 4 + 3], c4[3]);
                }
            }
#pragma unroll
            for (int kk = 0; kk < 4; ++kk)
                unsafeAtomicAdd(&smu[PR_OFF + kk * 64 + lane], c4[kk]);
            __syncthreads();
            if (tid < 256) {
                int kk = tid >> 6, ln = tid & 63;
                float l2 = smu[SC_OFF + 512 + ln];
#pragma unroll
                for (int u = 1; u < 8; ++u) l2 += smu[SC_OFF + 512 + u * 64 + ln];
                float val = smu[PR_OFF + kk * 64 + ln] / l2;
                stA(inp + (ll)(d0 + kk) * BB + bh * 64 + ln, val);
            }
            if (blk < 16) {
                int bi = tid >> 3, tj = tid & 7;
#pragma unroll
                for (int u = 0; u < 4; ++u) {
                    int tl = tj * 4 + u;
                    p.attnO[((ll)(bh * 64 + bi) * MLEN + s) * TT + jg * 32 + tl] = smu[SC_OFF + 1024 + tl * 65 + bi];
                }
            }
        }
        gbar(W, ++bar);

        // --- G0: decoder gru layer0 (K=1024: ctx then h0), weights resident rows 0..11 ---
        {
            smu[PR_OFF + tid] = 0.0f;
            smu[PR_OFF + 512 + tid] = 0.0f;
            __syncthreads();
            const int ctxw = (wv < 4);
            const float* stream = ctxw ? inp : h0s;
            const int ds0 = (wv & 3) * 128;
            const int tb = ctxw ? 0 : 512;
            float acc[12];
#pragma unroll
            for (int r = 0; r < 12; ++r) acc[r] = 0.0f;
            float av[2][8];
#pragma unroll
            for (int u = 0; u < 8; ++u) av[0][u] = ldA(stream + (ll)(ds0 + u) * BB + b2);
#pragma unroll
            for (int c = 0; c < 16; ++c) {
                const int cb = c & 1, pb = cb ^ 1;
                if (c < 15) {
                    const int dn = ds0 + (c + 1) * 8;
#pragma unroll
                    for (int u = 0; u < 8; ++u) av[pb][u] = ldA(stream + (ll)(dn + u) * BB + b2);
                }
                const int db = ds0 + c * 8;
#pragma unroll
                for (int h2 = 0; h2 < 2; ++h2) {
                    const int q4 = (tb + db + h2 * 4) >> 2;
#pragma unroll
                    for (int r = 0; r < 12; ++r) {
                        float4 w = t4[r * 256 + q4];
                        acc[r] = fmaf(w.x, av[cb][h2 * 4 + 0], acc[r]);
                        acc[r] = fmaf(w.y, av[cb][h2 * 4 + 1], acc[r]);
                        acc[r] = fmaf(w.z, av[cb][h2 * 4 + 2], acc[r]);
                        acc[r] = fmaf(w.w, av[cb][h2 * 4 + 3], acc[r]);
                    }
                }
            }
#pragma unroll
            for (int r = 0; r < 12; ++r) {
                int g = r >> 2;
                int prow = (g < 2) ? g * 4 : (ctxw ? 8 : 12);
                unsafeAtomicAdd(&smu[PR_OFF + (prow + (r & 3)) * 64 + lane], acc[r]);
            }
            __syncthreads();
            if (wv < 4) {
                int jl = wv, j = jg * 4 + jl;
                float* pr = smu + PR_OFF;
                int tokb = ldAi(tok + b2);
                float rs = T[(ll)j * 32 + tokb] + pr[(0 + jl) * 64 + lane] + p.dbih0[j] + p.dbhh0[j];
                float zs = T[(ll)(HH + j) * 32 + tokb] + pr[(4 + jl) * 64 + lane] + p.dbih0[HH + j] + p.dbhh0[HH + j];
                float ins = T[(ll)(2 * HH + j) * 32 + tokb] + pr[(8 + jl) * 64 + lane] + p.dbih0[2 * HH + j];
                float hns = pr[(12 + jl) * 64 + lane] + p.dbhh0[2 * HH + j];
                float r = sigf(rs), z = sigf(zs);
                float n = tanhf(ins + r * hns);
                float hp = ldA(h0s + (ll)j * BB + b2);
                stA(g0d + (ll)j * BB + b2, (1.0f - z) * n + z * hp);
            }
        }
        gbar(W, ++bar);

        // --- G1: decoder gru layer1 (K=1024: g0 then h1), weights resident rows 12..23 ---
        {
            smu[PR_OFF + tid] = 0.0f;
            smu[PR_OFF + 512 + tid] = 0.0f;
            __syncthreads();
            const int iw = (wv < 4);
            const float* stream = iw ? g0d : h1s;
            const int ds0 = (wv & 3) * 128;
            const int tb = iw ? 0 : 512;
            float acc[12];
#pragma unroll
            for (int r = 0; r < 12; ++r) acc[r] = 0.0f;
            float av[2][8];
#pragma unroll
            for (int u = 0; u < 8; ++u) av[0][u] = ldA(stream + (ll)(ds0 + u) * BB + b2);
#pragma unroll
            for (int c = 0; c < 16; ++c) {
                const int cb = c & 1, pb = cb ^ 1;
                if (c < 15) {
                    const int dn = ds0 + (c + 1) * 8;
#pragma unroll
                    for (int u = 0; u < 8; ++u) av[pb][u] = ldA(stream + (ll)(dn + u) * BB + b2);
                }
                const int db = ds0 + c * 8;
#pragma unroll
                for (int h2 = 0; h2 < 2; ++h2) {
                    const int q4 = (tb + db + h2 * 4) >> 2;
#pragma unroll
                    for (int r = 0; r < 12; ++r) {
                        float4 w = t4[(12 + r) * 256 + q4];
                        acc[r] = fmaf(w.x, av[cb][h2 * 4 + 0], acc[r]);
                        acc[r] = fmaf(w.y, av[cb][h2 * 4 + 1], acc[r]);
                        acc[r] = fmaf(w.z, av[cb][h2 * 4 + 2], acc[r]);
                        acc[r] = fmaf(w.w, av[cb][h2 * 4 + 3], acc[r]);
                    }
                }
            }
#pragma unroll
            for (int r = 0; r < 12; ++r) {
                int g = r >> 2;
                int prow = (g < 2) ? g * 4 : (iw ? 8 : 12);
                unsafeAtomicAdd(&smu[PR_OFF + (prow + (r & 3)) * 64 + lane], acc[r]);
            }
            __syncthreads();
            if (wv < 4) {
                int jl = wv, j = jg * 4 + jl;
                float* pr = smu + PR_OFF;
                float rs = pr[(0 + jl) * 64 + lane] + p.dbih1[j] + p.dbhh1[j];
                float zs = pr[(4 + jl) * 64 + lane] + p.dbih1[HH + j] + p.dbhh1[HH + j];
                float ins = pr[(8 + jl) * 64 + lane] + p.dbih1[2 * HH + j];
                float hns = pr[(12 + jl) * 64 + lane] + p.dbhh1[2 * HH + j];
                float r = sigf(rs), z = sigf(zs);
                float n = tanhf(ins + r * hns);
                float hp = ldA(h1s + (ll)j * BB + b2);
                stA(h1d + (ll)j * BB + b2, (1.0f - z) * n + z * hp);
            }
        }
        gbar(W, ++bar);

        // --- D: query (all blocks) + logits/argmax/tok (blocks 128..159, 4 b each) ---
        {
            const float* h1c = h1d;
            if (tid < 256) smu[PR_OFF + tid] = 0.0f;
            __syncthreads();
            {
                const int ds0 = wv * 64;
                float acc4[4] = {0, 0, 0, 0};
                float av[2][8];
#pragma unroll
                for (int u = 0; u < 8; ++u) av[0][u] = ldA(h1c + (ll)(ds0 + u) * BB + b2);
#pragma unroll
                for (int c = 0; c < 8; ++c) {
                    const int cb = c & 1, pb = cb ^ 1;
                    if (c < 7) {
                        const int dn = ds0 + (c + 1) * 8;
#pragma unroll
                        for (int u = 0; u < 8; ++u) av[pb][u] = ldA(h1c + (ll)(dn + u) * BB + b2);
                    }
                    const int db = ds0 + c * 8;
#pragma unroll
                    for (int h2 = 0; h2 < 2; ++h2) {
                        const int q4 = (db + h2 * 4) >> 2;
#pragma unroll
                        for (int jl = 0; jl < 4; ++jl) {
                            float4 w = t4q[jl * 128 + q4];
                            acc4[jl] = fmaf(w.x, av[cb][h2 * 4 + 0], acc4[jl]);
                            acc4[jl] = fmaf(w.y, av[cb][h2 * 4 + 1], acc4[jl]);
                            acc4[jl] = fmaf(w.z, av[cb][h2 * 4 + 2], acc4[jl]);
                            acc4[jl] = fmaf(w.w, av[cb][h2 * 4 + 3], acc4[jl]);
                        }
                    }
                }
#pragma unroll
                for (int jl = 0; jl < 4; ++jl)
                    unsafeAtomicAdd(&smu[PR_OFF + jl * 64 + lane], acc4[jl]);
            }
            __syncthreads();
            if (wv < 4) {
                int j = jg * 4 + wv;
                stA(qbm + (ll)j * BB + b2, smu[PR_OFF + wv * 64 + lane] + p.qb[j]);
            }
            if (blk >= 128 && blk < 160) {
                __syncthreads();
                const int bb = (blk - 128) * 4;
                // stage h1 slice [512 d][4 b] into SC
#pragma unroll
                for (int i = 0; i < 4; ++i) {
                    int f2 = i * 512 + tid;
                    int d = f2 >> 2, bi2 = f2 & 3;
                    smu[SC_OFF + f2] = ldA(h1c + (ll)d * BB + bb + bi2);
                }
                __syncthreads();
                if (tid < 128) {
                    const int bl = tid >> 5, v = tid & 31;
                    float acc = 0.0f;
                    for (int d4 = 0; d4 < 128; ++d4) {
                        float4 w4 = *(const float4*)(p.outW + (ll)v * HH + d4 * 4);
                        acc = fmaf(w4.x, smu[SC_OFF + (d4 * 4 + 0) * 4 + bl], acc);
                        acc = fmaf(w4.y, smu[SC_OFF + (d4 * 4 + 1) * 4 + bl], acc);
                        acc = fmaf(w4.z, smu[SC_OFF + (d4 * 4 + 2) * 4 + bl], acc);
                        acc = fmaf(w4.w, smu[SC_OFF + (d4 * 4 + 3) * 4 + bl], acc);
                    }
                    acc += p.outb[v];
                    p.vecO[((ll)(bb + bl) * MLEN + s) * VV + v] = acc;
                    smu[SC_OFF + 2048 + tid] = acc;
                }
                __syncthreads();
                if (tid < 4) {
                    int base = SC_OFF + 2048 + tid * 32;
                    float best = smu[base];
                    int bi2 = 0;
#pragma unroll
                    for (int u = 1; u < 32; ++u) {
                        float val = smu[base + u];
                        if (val > best) { best = val; bi2 = u; }
                    }
                    stAi(tok + bb + tid, bi2);
                }
            }
        }
        gbar(W, ++bar);
    }

    // ================= final hidden [2][128][512] =================
    {
        int idx = blk * 512 + tid;
        int l = idx >> 16, rr = idx & 65535;
        int b = rr >> 9, h = rr & 511;
        const float* src = l ? eh1 : (eh0 + SLOT);
        p.hidO[idx] = ldA(src + (ll)h * BB + b);
    }
}

extern "C" void kernel_launch(void* const* d_in, const int* in_sizes, int n_in,
                              void* d_out, int out_size, void* d_ws, size_t ws_size,
                              hipStream_t stream) {
    (void)in_sizes; (void)n_in; (void)out_size; (void)ws_size;
    P prm;
    prm.x     = (const float*)d_in[0];
    prm.emb   = (const float*)d_in[1];
    prm.eWih0 = (const float*)d_in[2];
    prm.eWhh0 = (const float*)d_in[3];
    prm.ebih0 = (const float*)d_in[4];
    prm.ebhh0 = (const float*)d_in[5];
    prm.eWih1 = (const float*)d_in[6];
    prm.eWhh1 = (const float*)d_in[7];
    prm.ebih1 = (const float*)d_in[8];
    prm.ebhh1 = (const float*)d_in[9];
    prm.dWih0 = (const float*)d_in[10];
    prm.dWhh0 = (const float*)d_in[11];
    prm.dbih0 = (const float*)d_in[12];
    prm.dbhh0 = (const float*)d_in[13];
    prm.dWih1 = (const float*)d_in[14];
    prm.dWhh1 = (const float*)d_in[15];
    prm.dbih1 = (const float*)d_in[16];
    prm.dbhh1 = (const float*)d_in[17];
    prm.qW    = (const float*)d_in[18];
    prm.qb    = (const float*)d_in[19];
    prm.outW  = (const float*)d_in[20];
    prm.outb  = (const float*)d_in[21];
    prm.ws    = (float*)d_ws;
    prm.vecO  = (float*)d_out;
    prm.hidO  = prm.vecO + (ll)BB * MLEN * VV;
    prm.attnO = prm.hidO + (ll)2 * BB * HH;

    hipMemsetAsync(d_ws, 0, 16384, stream);  // barrier gen + tree counters
    void* args[] = { &prm };
    hipLaunchCooperativeKernel((void*)kmain, dim3(256), dim3(512), args, 0, stream);
}